// Round 6
// baseline (940.124 us; speedup 1.0000x reference)
//
#include <hip/hip_runtime.h>

#define SEQ   2048
#define BATCH 4096
#define HID   6
#define BLK   256            // 8 elements/block (32 lanes each)
#define EPB   (BLK / 32)     // elements per block

typedef float v2 __attribute__((ext_vector_type(2)));
typedef unsigned u2 __attribute__((ext_vector_type(2)));

// ---- fast HW math (v_exp_f32 / v_rcp_f32), with asm fallback ----
__device__ __forceinline__ float fexp2(float a) {
#if __has_builtin(__builtin_amdgcn_exp2f)
  return __builtin_amdgcn_exp2f(a);
#else
  float r; asm("v_exp_f32 %0, %1" : "=v"(r) : "v"(a)); return r;
#endif
}
__device__ __forceinline__ float frcp(float a) {
#if __has_builtin(__builtin_amdgcn_rcpf)
  return __builtin_amdgcn_rcpf(a);
#else
  float r; asm("v_rcp_f32 %0, %1" : "=v"(r) : "v"(a)); return r;
#endif
}

// ---- DPP cross-lane move (VALU pipe, no LDS) ----
template <int CTRL>
__device__ __forceinline__ float dppf(float v) {
  int r = __builtin_amdgcn_update_dpp(0, __builtin_bit_cast(int, v), CTRL, 0xF, 0xF, true);
  return __builtin_bit_cast(float, r);
}

// xor16 lane exchange via gfx950 v_permlane16_swap_b32 (VALU pipe).
// Semantics assumed: new D.row1 = old S.row0, new S.row0 = old D.row1 (and
// rows 3/2 likewise). With D=S=v: D' rows = [r0,r0,r2,r2], S' = [r1,r1,r3,r3];
// lane with bit4 set takes D', else S'.
__device__ __forceinline__ float xor16f(float v, bool hi) {
#if __has_builtin(__builtin_amdgcn_permlane16_swap)
  u2 r = __builtin_amdgcn_permlane16_swap(__builtin_bit_cast(unsigned, v),
                                          __builtin_bit_cast(unsigned, v), false, false);
  return __builtin_bit_cast(float, hi ? r.x : r.y);
#else
  unsigned d = __builtin_bit_cast(unsigned, v), s = d;
  asm volatile("v_permlane16_swap_b32 %0, %1" : "+v"(d), "+v"(s));
  return __builtin_bit_cast(float, hi ? d : s);
#endif
}

__global__ __launch_bounds__(BLK, 1) void lstm2_kernel(
    const float* __restrict__ x,
    const float* __restrict__ Wih0, const float* __restrict__ Whh0,
    const float* __restrict__ bih0, const float* __restrict__ bhh0,
    const float* __restrict__ Wih1, const float* __restrict__ Whh1,
    const float* __restrict__ bih1, const float* __restrict__ bhh1,
    const float* __restrict__ W2,   const float* __restrict__ b2,
    float* __restrict__ out)
{
  __shared__ float obuf[64][EPB];   // output row buffer (keeps stores off the loop)

  const int tidb = threadIdx.x;
  const int g    = tidb >> 5;            // element within block
  const int b    = blockIdx.x * EPB + g; // batch element
  const int l5   = tidb & 31;            // lane within element
  const int u    = l5 & 7;               // unit 0..7 (6,7 pads)
  const int q    = l5 >> 3;              // gate: 0=i 1=f 2=g 3=o
  const bool hi16 = (l5 & 16) != 0;
  const int uu   = (u < HID) ? u : (HID - 1);
  const int row  = q * HID + uu;         // row in 4H gate matrix

  // activation constants: sigmoid (i,f,o) / tanh (g) via A*sigmoid(A*a)+Bc.
  // K folded into weights+bias so exp2 input needs no extra multiply.
  const float Aq = (q == 2) ? 2.f : 1.f;
  const float Bq = (q == 2) ? -1.f : 0.f;
  const float Kq = -1.4426950408889634f * Aq;
  const float KT =  2.8853900817779268f;   // tanh(c) = 1 - 2/(1+exp2(KT*c))

  // K-scaled weights in xor-relative pairs: w[k] = {W[u^2k], W[u^2k+1]}
  v2 wh0[4], wi1[4], wh1[4], w2r[4];
#pragma unroll
  for (int k = 0; k < 4; ++k) {
    const int k0 = u ^ (2 * k), k1 = u ^ (2 * k + 1);
    const bool ok0 = (k0 < HID), ok1 = (k1 < HID);
    wh0[k] = v2{ok0 ? Kq * Whh0[row * HID + k0] : 0.f, ok1 ? Kq * Whh0[row * HID + k1] : 0.f};
    wi1[k] = v2{ok0 ? Kq * Wih1[row * HID + k0] : 0.f, ok1 ? Kq * Wih1[row * HID + k1] : 0.f};
    wh1[k] = v2{ok0 ? Kq * Whh1[row * HID + k0] : 0.f, ok1 ? Kq * Whh1[row * HID + k1] : 0.f};
    w2r[k] = v2{ok0 ? W2[k0] : 0.f,                    ok1 ? W2[k1] : 0.f};
  }
  const v2 wx = v2{Kq * Wih0[row * 2 + 0], Kq * Wih0[row * 2 + 1]};
  const v2 B0 = v2{Kq * (bih0[row] + bhh0[row]), 0.f};
  const v2 B1 = v2{Kq * (bih1[row] + bhh1[row]), 0.f};
  const float bout = b2[0];

  float c0 = 0.f, c1 = 0.f;
  float h0p = 0.f, h1p = 0.f;
  v2 h0g[4], h1g[4];

  // one layer-step: a (pre-scaled by K) -> gate value, exchange i/f/g/o across
  // q-lanes (xor8 = row_ror:8 exact; xor16 = permlane16_swap; xor24 = both),
  // c/h update replicated in all 4 q-lanes.
  auto lstep = [&](float a, float& c) -> float {
    float gv = fmaf(Aq, frcp(1.f + fexp2(a)), Bq);
    float t8  = dppf<0x128>(gv);
    float t16 = xor16f(gv, hi16);
    float t24 = dppf<0x128>(t16);
    // per-q roles: q0: gv=i t8=f t16=g t24=o | q1: gv=f t8=i t16=o t24=g
    //              q2: gv=g t8=o t16=i t24=f | q3: gv=o t8=g t16=f t24=i
    float m  = (q & 1) ? t8 * t24 : gv * t16;                  // i*g
    float fg = (q & 1) ? ((q & 2) ? t16 : gv) : ((q & 2) ? t24 : t8);   // f
    float og = (q & 1) ? ((q & 2) ? gv : t16) : ((q & 2) ? t8 : t24);   // o
    c = fmaf(fg, c, m);
    float th = fmaf(-2.f, frcp(1.f + fexp2(c * KT)), 1.f);
    return og * th;
  };

  // all-gather h over units into xor-relative pairs g[k] = {h[u^2k], h[u^2k+1]}
  // (h replicated across q-lanes, so row_ror:4 == xor4 within each 16-row)
  auto gath = [&](float h, v2 (&g)[4]) {
    float t1 = dppf<0xB1>(h);        // xor1
    float t2 = dppf<0x4E>(h);        // xor2
    float t3 = dppf<0x4E>(t1);       // xor3
    g[0] = v2{h, t1};
    g[1] = v2{t2, t3};
    g[2] = v2{dppf<0x124>(h),  dppf<0x124>(t1)};   // xor4/5
    g[3] = v2{dppf<0x124>(t2), dppf<0x124>(t3)};   // xor6/7
  };

  auto doth = [](const v2 (&w)[4], const v2 (&g)[4], v2 acc) -> v2 {
#pragma unroll
    for (int k = 0; k < 4; ++k) acc = __builtin_elementwise_fma(w[k], g[k], acc);
    return acc;
  };

  // bulk flush: 64 rows x EPB elements, float2 per thread
  auto flush = [&](int rbase) {
    const int r = tidb >> 2, j = (tidb & 3) * 2;
    float2 vv = *(const float2*)&obuf[r][j];
    *(float2*)&out[(size_t)(rbase + r) * BATCH + blockIdx.x * EPB + j] = vv;
  };

  const v2* x2 = (const v2*)x;
  // x prefetch queue, depth 4
  v2 xc  = x2[(size_t)0 * BATCH + b];
  v2 xn1 = x2[(size_t)1 * BATCH + b];
  v2 xn2 = x2[(size_t)2 * BATCH + b];
  v2 xn3 = x2[(size_t)3 * BATCH + b];

  // t = 0 peel: L0 only (h0[-1] = 0)
  {
    v2 A0 = __builtin_elementwise_fma(wx, xc, B0);
    h0p = lstep(A0.x + A0.y, c0);
    v2 xf = x2[(size_t)4 * BATCH + b];
    xc = xn1; xn1 = xn2; xn2 = xn3; xn3 = xf;
  }

  // iteration t: L0[t] (x[t], h0[t-1]) || L1[t-1] (h0[t-1], h1[t-2])
#pragma unroll 1
  for (int t = 1; t < SEQ; ++t) {
    int tf = t + 4; tf = (tf < SEQ) ? tf : (SEQ - 1);
    v2 xf = x2[(size_t)tf * BATCH + b];

    gath(h0p, h0g);   // h0[t-1]
    gath(h1p, h1g);   // h1[t-2]

    v2 A0 = doth(wh0, h0g, __builtin_elementwise_fma(wx, xc, B0));
    v2 A1 = doth(wh1, h1g, doth(wi1, h0g, B1));

    if (t >= 2) {
      const int r = t - 2;
      v2 AO = doth(w2r, h1g, v2{bout, 0.f});
      if (l5 == 0) obuf[r & 63][g] = AO.x + AO.y;
      if ((r & 63) == 63) {          // uniform branch
        __syncthreads();
        flush(r - 63);
        __syncthreads();
      }
    }

    float h0c = lstep(A0.x + A0.y, c0);   // h0[t]
    float h1c = lstep(A1.x + A1.y, c1);   // h1[t-1]

    h0p = h0c; h1p = h1c;
    xc = xn1; xn1 = xn2; xn2 = xn3; xn3 = xf;
  }

  // epilogue: rows S-2 and S-1 -> slots 62, 63, then final flush
  {
    gath(h0p, h0g);   // h0[S-1]
    gath(h1p, h1g);   // h1[S-2]
    {
      v2 AO = doth(w2r, h1g, v2{bout, 0.f});
      if (l5 == 0) obuf[62][g] = AO.x + AO.y;
    }
    v2 A1 = doth(wh1, h1g, doth(wi1, h0g, B1));
    float h1c = lstep(A1.x + A1.y, c1);   // h1[S-1]
    gath(h1c, h1g);
    v2 AO = doth(w2r, h1g, v2{bout, 0.f});
    if (l5 == 0) obuf[63][g] = AO.x + AO.y;
    __syncthreads();
    flush(SEQ - 64);
  }
}

extern "C" void kernel_launch(void* const* d_in, const int* in_sizes, int n_in,
                              void* d_out, int out_size, void* d_ws, size_t ws_size,
                              hipStream_t stream) {
  const float* x    = (const float*)d_in[0];
  const float* Wih0 = (const float*)d_in[1];
  const float* Whh0 = (const float*)d_in[2];
  const float* bih0 = (const float*)d_in[3];
  const float* bhh0 = (const float*)d_in[4];
  const float* Wih1 = (const float*)d_in[5];
  const float* Whh1 = (const float*)d_in[6];
  const float* bih1 = (const float*)d_in[7];
  const float* bhh1 = (const float*)d_in[8];
  const float* W2   = (const float*)d_in[9];
  const float* b2   = (const float*)d_in[10];
  float* out = (float*)d_out;

  dim3 grid(BATCH / EPB);   // 512 blocks x 4 waves = 2048 waves = 2 waves/SIMD
  dim3 block(BLK);
  hipLaunchKernelGGL(lstm2_kernel, grid, block, 0, stream,
                     x, Wih0, Whh0, bih0, bhh0, Wih1, Whh1, bih1, bhh1, W2, b2, out);
}

// Round 7
// 621.023 us; speedup vs baseline: 1.5138x; 1.5138x over previous
//
#include <hip/hip_runtime.h>

#define SEQ   2048
#define BATCH 4096
#define HID   6
#define BLK   256   // 4 waves/block; 256 blocks -> 1 block/CU, 1 wave/SIMD

typedef float v2f __attribute__((ext_vector_type(2)));
typedef unsigned u2 __attribute__((ext_vector_type(2)));

// ---- fast HW math ----
__device__ __forceinline__ float fexp2(float a) {
#if __has_builtin(__builtin_amdgcn_exp2f)
  return __builtin_amdgcn_exp2f(a);
#else
  float r; asm("v_exp_f32 %0, %1" : "=v"(r) : "v"(a)); return r;
#endif
}
__device__ __forceinline__ float frcp(float a) {
#if __has_builtin(__builtin_amdgcn_rcpf)
  return __builtin_amdgcn_rcpf(a);
#else
  float r; asm("v_rcp_f32 %0, %1" : "=v"(r) : "v"(a)); return r;
#endif
}

// ds_swizzle broadcast of lane (8k-group base + J) to the whole 8-group:
// BitMode offset = (xor<<10)|(or<<5)|and ; and=0x18 keeps group, or=J selects lane.
template <int OFF>
__device__ __forceinline__ float swzf(float v) {
  int r = __builtin_amdgcn_ds_swizzle(__builtin_bit_cast(int, v), OFF);
  return __builtin_bit_cast(float, r);
}
#define BC0 0x18
#define BC1 0x38
#define BC2 0x58
#define BC3 0x78
#define BC4 0x98
#define BC5 0xB8

// lane l <-> l^32 exchange via v_permlane32_swap_b32.
// With D=S=v: new D rows[2,3] = old S rows[0,1] -> D' = [lo32,lo32], S' = [hi32,hi32].
// hi lanes take D', lo lanes take S' (same select pattern as R6's verified 16-swap).
__device__ __forceinline__ float xhalf(float v, bool hi) {
#if __has_builtin(__builtin_amdgcn_permlane32_swap)
  u2 r = __builtin_amdgcn_permlane32_swap(__builtin_bit_cast(unsigned, v),
                                          __builtin_bit_cast(unsigned, v), false, false);
  return __builtin_bit_cast(float, hi ? r.x : r.y);
#else
  unsigned d = __builtin_bit_cast(unsigned, v), s = d;
  asm volatile("v_permlane32_swap_b32 %0, %1" : "+v"(d), "+v"(s));
  return __builtin_bit_cast(float, hi ? d : s);
#endif
}

__global__ __launch_bounds__(BLK, 1) void lstm2_kernel(
    const float* __restrict__ x,
    const float* __restrict__ Wih0, const float* __restrict__ Whh0,
    const float* __restrict__ bih0, const float* __restrict__ bhh0,
    const float* __restrict__ Wih1, const float* __restrict__ Whh1,
    const float* __restrict__ bih1, const float* __restrict__ bhh1,
    const float* __restrict__ W2,   const float* __restrict__ b2,
    float* __restrict__ out)
{
  __shared__ float obuf[64][16];   // output rows staged; bulk-flushed every 64 steps

  const int tid = threadIdx.x;
  const int wib = tid >> 6;            // wave in block 0..3
  const int l6  = tid & 63;
  const bool hi = l6 >= 32;            // false: layer-0 lanes, true: layer-1 lanes
  const int j   = l6 & 31;
  const int el  = j >> 3;              // element within wave 0..3
  const int u   = j & 7;               // unit 0..7 (6,7 pads)
  const int uu  = (u < HID) ? u : (HID - 1);
  const int b   = blockIdx.x * 16 + wib * 4 + el;   // batch element

  // Per-row constants, rows q = 0..3 (i,f,g,o). Gate scale K folded into
  // weights+bias: sigmoid rows K=-log2e, tanh row (q=2) K=-2*log2e.
  // v1-dot: layer0 = x (pair0 only), layer1 = h0g. v2-dot: own-layer h recurrence.
  v2f WA[4][3], WB[4][3];
  float BS[4];
#pragma unroll
  for (int q = 0; q < 4; ++q) {
    const int rq = q * HID + uu;
    const float Kq = (q == 2) ? -2.8853900817779268f : -1.4426950408889634f;
    if (!hi) {
      WA[q][0] = v2f{Kq * Wih0[rq * 2 + 0], Kq * Wih0[rq * 2 + 1]};
      WA[q][1] = v2f{0.f, 0.f};
      WA[q][2] = v2f{0.f, 0.f};
#pragma unroll
      for (int k = 0; k < 3; ++k)
        WB[q][k] = v2f{Kq * Whh0[rq * HID + 2 * k], Kq * Whh0[rq * HID + 2 * k + 1]};
      BS[q] = Kq * (bih0[rq] + bhh0[rq]);
    } else {
#pragma unroll
      for (int k = 0; k < 3; ++k) {
        WA[q][k] = v2f{Kq * Wih1[rq * HID + 2 * k], Kq * Wih1[rq * HID + 2 * k + 1]};
        WB[q][k] = v2f{Kq * Whh1[rq * HID + 2 * k], Kq * Whh1[rq * HID + 2 * k + 1]};
      }
      BS[q] = Kq * (bih1[rq] + bhh1[rq]);
    }
  }
  const v2f w2p0 = v2f{W2[0], W2[1]}, w2p1 = v2f{W2[2], W2[3]}, w2p2 = v2f{W2[4], W2[5]};
  const float bout = b2[0];
  const float KT = 2.8853900817779268f;   // tanh(c) = 1 - 2*rcp(1+exp2(KT*c))

  float h = 0.f, c = 0.f;   // own-layer state: lo = (h0,c0), hi = (h1,c1)

  // absolute-order gather of own-group h (lanes 0..5 real) into 3 pairs
  auto gath = [&](float hv, v2f (&g)[3]) {
    g[0] = v2f{swzf<BC0>(hv), swzf<BC1>(hv)};
    g[1] = v2f{swzf<BC2>(hv), swzf<BC3>(hv)};
    g[2] = v2f{swzf<BC4>(hv), swzf<BC5>(hv)};
  };

  // one fused step: lo computes L0 cell (x, h0-rec), hi computes L1 cell
  // (h0 via permlane swap, h1-rec). Also returns the out-dot of hi's v2
  // gather (= h1[t-2] row value).
  auto step = [&](v2f xc, float& ov) {
    v2f g2[3]; gath(h, g2);                 // own-layer recurrence input
    float hs = xhalf(h, hi);                // hi lanes: partner h0[t-1]
    v2f g1[3]; gath(hs, g1);                // L1's input-gather (lo: garbage)
    v2f v10 = hi ? g1[0] : xc;              // lo: x-pair (WA[..][1,2]=0)

    float a[4];
#pragma unroll
    for (int q = 0; q < 4; ++q) {
      v2f acc = v2f{BS[q], 0.f};
      acc = __builtin_elementwise_fma(WA[q][0], v10,   acc);
      acc = __builtin_elementwise_fma(WA[q][1], g1[1], acc);
      acc = __builtin_elementwise_fma(WA[q][2], g1[2], acc);
      acc = __builtin_elementwise_fma(WB[q][0], g2[0], acc);
      acc = __builtin_elementwise_fma(WB[q][1], g2[1], acc);
      acc = __builtin_elementwise_fma(WB[q][2], g2[2], acc);
      a[q] = acc.x + acc.y;
    }
    // output row dot from hi's g2 = h1g[t-2]
    v2f ao = __builtin_elementwise_fma(w2p0, g2[0],
             __builtin_elementwise_fma(w2p1, g2[1],
             __builtin_elementwise_fma(w2p2, g2[2], v2f{bout, 0.f})));
    ov = ao.x + ao.y;

    // gates: a pre-scaled so sigma = rcp(1+exp2(a)); g-gate = 2*sigma-1
    float i_ = frcp(1.f + fexp2(a[0]));
    float f_ = frcp(1.f + fexp2(a[1]));
    float g_ = fmaf(2.f, frcp(1.f + fexp2(a[2])), -1.f);
    float o_ = frcp(1.f + fexp2(a[3]));
    c = fmaf(f_, c, i_ * g_);
    float th = fmaf(-2.f, frcp(1.f + fexp2(c * KT)), 1.f);
    h = o_ * th;
  };

  // bulk flush: 64 rows x 16 elements as float4 per thread (full 64B lines)
  auto flush = [&](int rbase) {
    const int r = tid >> 2, jj = (tid & 3) * 4;
    float4 vv = *(const float4*)&obuf[r][jj];
    *(float4*)&out[(size_t)(rbase + r) * BATCH + blockIdx.x * 16 + jj] = vv;
  };

  const v2f* x2 = (const v2f*)x;
  // x prefetch queue, depth 4; invariant at loop-entry t: (xc..xn3) = x[t..t+3]
  v2f xc  = x2[(size_t)0 * BATCH + b];
  v2f xn1 = x2[(size_t)1 * BATCH + b];
  v2f xn2 = x2[(size_t)2 * BATCH + b];
  v2f xn3 = x2[(size_t)3 * BATCH + b];

  // t = 0 peel: lo computes h0[0]; hi's result is pre-sequence garbage -> reset
  {
    float ov;
    step(xc, ov);
    if (hi) { h = 0.f; c = 0.f; }
    v2f xf = x2[(size_t)4 * BATCH + b];
    xc = xn1; xn1 = xn2; xn2 = xn3; xn3 = xf;
  }

  // iteration t: lo -> h0[t] (x[t], h0[t-1]); hi -> h1[t-1] (h0[t-1], h1[t-2]);
  // out row t-2 from hi's recurrence gather.
#pragma unroll 1
  for (int t = 1; t < SEQ; ++t) {
    int tf = t + 4; tf = (tf < SEQ) ? tf : (SEQ - 1);
    v2f xf = x2[(size_t)tf * BATCH + b];

    float ov;
    step(xc, ov);

    if (t >= 2) {
      const int r = t - 2;
      if (hi && u == 0) obuf[r & 63][wib * 4 + el] = ov;
      if ((r & 63) == 63) {          // uniform branch
        __syncthreads();
        flush(r - 63);
        __syncthreads();
      }
    }
    xc = xn1; xn1 = xn2; xn2 = xn3; xn3 = xf;
  }

  // epilogue: one more fused step gives h1[S-1] and out row S-2; then the
  // final gather gives row S-1. Flush slots 62,63 with the last 64 rows.
  {
    float ov;
    step(xc, ov);                    // hi: h <- h1[S-1], ov = row S-2 value
    if (hi && u == 0) obuf[62][wib * 4 + el] = ov;
    v2f g2[3]; gath(h, g2);          // hi: h1[S-1] gathered
    v2f ao = __builtin_elementwise_fma(w2p0, g2[0],
             __builtin_elementwise_fma(w2p1, g2[1],
             __builtin_elementwise_fma(w2p2, g2[2], v2f{bout, 0.f})));
    if (hi && u == 0) obuf[63][wib * 4 + el] = ao.x + ao.y;
    __syncthreads();
    flush(SEQ - 64);
  }
}

extern "C" void kernel_launch(void* const* d_in, const int* in_sizes, int n_in,
                              void* d_out, int out_size, void* d_ws, size_t ws_size,
                              hipStream_t stream) {
  const float* x    = (const float*)d_in[0];
  const float* Wih0 = (const float*)d_in[1];
  const float* Whh0 = (const float*)d_in[2];
  const float* bih0 = (const float*)d_in[3];
  const float* bhh0 = (const float*)d_in[4];
  const float* Wih1 = (const float*)d_in[5];
  const float* Whh1 = (const float*)d_in[6];
  const float* bih1 = (const float*)d_in[7];
  const float* bhh1 = (const float*)d_in[8];
  const float* W2   = (const float*)d_in[9];
  const float* b2   = (const float*)d_in[10];
  float* out = (float*)d_out;

  dim3 grid(BATCH / 16);   // 256 blocks x 4 waves = 1024 waves = 1 wave/SIMD
  dim3 block(BLK);
  hipLaunchKernelGGL(lstm2_kernel, grid, block, 0, stream,
                     x, Wih0, Whh0, bih0, bhh0, Wih1, Whh1, bih1, bhh1, W2, b2, out);
}